// Round 8
// baseline (523.935 us; speedup 1.0000x reference)
//
#include <hip/hip_runtime.h>
#include <hip/hip_cooperative_groups.h>
#include <math.h>

namespace cg = cooperative_groups;

// Problem constants (from reference setup_inputs)
#define N_EDGES   150000
#define TOTAL     300000            // pos + neg scored edges
#define EMBED_DIM 512
#define N_NODES   50000
#define TABLE_ELEMS (N_NODES * EMBED_DIM)          // 25,600,000
#define TABLE_BYTES_F8 ((size_t)TABLE_ELEMS)       // 25,600,000 (1 B/elem)
#define BLOCK_THREADS 256
#define CONV_BLOCKS 2048

#define GROUPS16   (TOTAL / 16)     // 18750 groups of 16 edges
#define POS_G16    (N_EDGES / 16)   // 9375: groups < POS_G16 are all-positive

// ---- chunked (L2-resident) path geometry ----
#define NCHUNK       8
#define CHUNK_BYTES  64                                  // 64 fp8 dims per row per chunk
#define NODE_UNITS   (N_NODES * 16)                      // 800000 4-float units per chunk
#define CONV_BLOCKS_EXACT (NODE_UNITS / BLOCK_THREADS)   // 3125: one unit per thread
#define SLICE_BYTES  ((size_t)N_NODES * CHUNK_BYTES)     // 3.2 MB: fits one XCD's 4 MiB L2
#define PARTIAL_BYTES ((size_t)NCHUNK * TOTAL * 4)       // 9.6 MB fp32 partial scores
#define WS_ACC_OFF   (TABLE_BYTES_F8 + PARTIAL_BYTES)    // 35,200,000
#define WS_NEEDED    (WS_ACC_OFF + 64)

#define SCORE_BLOCKS 2048
#define WAVES_PER_CHUNK 1024        // standalone: (2048/8 blocks) * 4 waves
#define NB4      ((GROUPS16 + 3) / 4)   // 4688 4-group spans per chunk
#define RED_BLOCKS ((TOTAL + BLOCK_THREADS - 1) / BLOCK_THREADS)    // 1172

// fused cooperative geometry: 1024 blocks x 256 thr, launch_bounds(256,4)
// -> VGPR<=128 -> 4 blocks/CU x 256 CU = 1024 co-resident (coop check passes)
#define FUSED_BLOCKS 1024
#define FUSED_WPC    512            // (1024/8 blocks) * 4 waves per chunk

typedef float floatx4 __attribute__((ext_vector_type(4)));
typedef float floatx2 __attribute__((ext_vector_type(2)));
typedef unsigned long long ull;
typedef ull ull2 __attribute__((ext_vector_type(2)));
typedef int  intx2 __attribute__((ext_vector_type(2)));   // clang vector: OK for NT builtins

// ---- convert body: one (node,w4) unit -> 8 chunk-major fp8 words ----
__device__ __forceinline__ void convert_unit(
    const floatx4* __restrict__ in, int* __restrict__ out, int u)
{
    const int node = u >> 4;
    const int w4   = u & 15;
    const floatx4* __restrict__ src = in + node * 128 + w4;
    #pragma unroll
    for (int c = 0; c < NCHUNK; c++) {
        floatx4 v = __builtin_nontemporal_load(src + c * 16);
        int r = 0;
        r = __builtin_amdgcn_cvt_pk_fp8_f32(v[0], v[1], r, false);  // bytes 0-1
        r = __builtin_amdgcn_cvt_pk_fp8_f32(v[2], v[3], r, true);   // bytes 2-3
        __builtin_nontemporal_store(r, out + c * NODE_UNITS + u);
    }
}

// ---- 8-contiguous-group scoring unit: 2 wide idx loads + 16 NT gathers + ONE
// wide store. Gathers are NONTEMPORAL this round (round-7 post-mortem: wall is
// the per-CU L1 miss queue at ~7 cy/line; NT loads skip L1 allocation).
// k-permutation diagonal trick: A and B fragments share the lane->dim map so
// any k-bijection cancels in dot(src_i, dst_i); C[i][i] = score of edge i.
__device__ __forceinline__ void score8(
    int gb, int i, int quad, int half, int sl8, bool is_diag, int dreg,
    const unsigned char* __restrict__ slice,
    const int* __restrict__ pos_edges, const int* __restrict__ neg_edges,
    float* __restrict__ pout)
{
    int s[8], t[8];
    const bool widepos = (gb + 8 <= POS_G16);
    const bool wideneg = (gb >= POS_G16) && (16 * gb + 128 <= 2 * N_EDGES);
    if (widepos || wideneg) {
        const int* __restrict__ ed = widepos ? pos_edges : neg_edges;
        const int e0 = 16 * gb - (widepos ? 0 : N_EDGES);
        const int lane = threadIdx.x & 63;
        const intx2 sv = __builtin_nontemporal_load((const intx2*)(ed + e0) + lane);
        const intx2 tv = __builtin_nontemporal_load((const intx2*)(ed + N_EDGES + e0) + lane);
        #pragma unroll
        for (int j = 0; j < 8; j++) {
            // edge (16j+i) lives in lane 8j+(i>>1), component i&1
            const int sx = __shfl(sv[0], 8 * j + sl8, 64);
            const int sy = __shfl(sv[1], 8 * j + sl8, 64);
            s[j] = half ? sy : sx;
            const int tx = __shfl(tv[0], 8 * j + sl8, 64);
            const int ty = __shfl(tv[1], 8 * j + sl8, 64);
            t[j] = half ? ty : tx;
        }
    } else {
        #pragma unroll
        for (int j = 0; j < 8; j++) {
            int g = gb + j;
            if (g > GROUPS16 - 1) g = GROUPS16 - 1;   // tail clamp (stores guarded)
            const bool ip = (g < POS_G16);
            const int* __restrict__ ed = ip ? pos_edges : neg_edges;
            const int e0 = 16 * g - (ip ? 0 : N_EDGES);
            s[j] = __builtin_nontemporal_load(ed + e0 + i);
            t[j] = __builtin_nontemporal_load(ed + N_EDGES + e0 + i);
        }
    }
    ull2 a[8], b[8];
    #pragma unroll
    for (int j = 0; j < 8; j++) {
        a[j] = __builtin_nontemporal_load(
            (const ull2*)(slice + (size_t)(unsigned)s[j] * CHUNK_BYTES + quad * 16));
        b[j] = __builtin_nontemporal_load(
            (const ull2*)(slice + (size_t)(unsigned)t[j] * CHUNK_BYTES + quad * 16));
    }
#if __has_builtin(__builtin_amdgcn_sched_barrier)
    __builtin_amdgcn_sched_barrier(0);   // keep the 16-gather batch intact
#endif
    float scv[8];
    #pragma unroll
    for (int j = 0; j < 8; j++) {
        floatx4 C = {0, 0, 0, 0};
        C = __builtin_amdgcn_mfma_f32_16x16x32_fp8_fp8((long)a[j][0], (long)b[j][0], C, 0, 0, 0);
        C = __builtin_amdgcn_mfma_f32_16x16x32_fp8_fp8((long)a[j][1], (long)b[j][1], C, 0, 0, 0);
        scv[j] = (dreg == 0) ? C[0] : (dreg == 1) ? C[1] : (dreg == 2) ? C[2] : C[3];
    }
    if (gb + 8 <= GROUPS16) {
        // in-register transpose: lane l takes floats (2l,2l+1) of the 128-float
        // window (group j=l>>3, edges i0=(2l)&15, i0+1; diag lanes src0,src0+1).
        const int lane = threadIdx.x & 63;
        const int i0   = (2 * lane) & 15;
        const int src0 = ((i0 >> 2) << 4) + i0;
        const int jsel = lane >> 3;
        float o0 = 0.0f, o1 = 0.0f;
        #pragma unroll
        for (int j = 0; j < 8; j++) {
            const float t0 = __shfl(scv[j], src0, 64);
            const float t1 = __shfl(scv[j], src0 + 1, 64);
            if (jsel == j) { o0 = t0; o1 = t1; }
        }
        floatx2 o = { o0, o1 };
        __builtin_nontemporal_store(o, (floatx2*)(pout + 16 * gb) + lane);
    } else {
        #pragma unroll
        for (int j = 0; j < 8; j++) {
            const int g = gb + j;
            if (is_diag && g < GROUPS16)
                __builtin_nontemporal_store(scv[j], pout + 16 * g + i);
        }
    }
}

// ---- 4-group tail unit ----
__device__ __forceinline__ void score4(
    int gb, int i, int quad, bool is_diag, int dreg,
    const unsigned char* __restrict__ slice,
    const int* __restrict__ pos_edges, const int* __restrict__ neg_edges,
    float* __restrict__ pout)
{
    int s[4], t[4];
    const bool widepos = (gb + 4 <= POS_G16);
    const bool wideneg = (gb >= POS_G16) && (16 * gb + 64 <= 2 * N_EDGES);
    if (widepos || wideneg) {
        const int* __restrict__ ed = widepos ? pos_edges : neg_edges;
        const int e0 = 16 * gb - (widepos ? 0 : N_EDGES);
        const int lane = threadIdx.x & 63;
        const int sv = __builtin_nontemporal_load(ed + e0 + lane);
        const int tv = __builtin_nontemporal_load(ed + N_EDGES + e0 + lane);
        #pragma unroll
        for (int j = 0; j < 4; j++) {
            s[j] = __shfl(sv, 16 * j + i, 64);
            t[j] = __shfl(tv, 16 * j + i, 64);
        }
    } else {
        #pragma unroll
        for (int j = 0; j < 4; j++) {
            int g = gb + j;
            if (g > GROUPS16 - 1) g = GROUPS16 - 1;
            const bool ip = (g < POS_G16);
            const int* __restrict__ ed = ip ? pos_edges : neg_edges;
            const int e0 = 16 * g - (ip ? 0 : N_EDGES);
            s[j] = __builtin_nontemporal_load(ed + e0 + i);
            t[j] = __builtin_nontemporal_load(ed + N_EDGES + e0 + i);
        }
    }
    ull2 a[4], b[4];
    #pragma unroll
    for (int j = 0; j < 4; j++) {
        a[j] = __builtin_nontemporal_load(
            (const ull2*)(slice + (size_t)(unsigned)s[j] * CHUNK_BYTES + quad * 16));
        b[j] = __builtin_nontemporal_load(
            (const ull2*)(slice + (size_t)(unsigned)t[j] * CHUNK_BYTES + quad * 16));
    }
#if __has_builtin(__builtin_amdgcn_sched_barrier)
    __builtin_amdgcn_sched_barrier(0);
#endif
    float scv[4];
    #pragma unroll
    for (int j = 0; j < 4; j++) {
        floatx4 C = {0, 0, 0, 0};
        C = __builtin_amdgcn_mfma_f32_16x16x32_fp8_fp8((long)a[j][0], (long)b[j][0], C, 0, 0, 0);
        C = __builtin_amdgcn_mfma_f32_16x16x32_fp8_fp8((long)a[j][1], (long)b[j][1], C, 0, 0, 0);
        scv[j] = (dreg == 0) ? C[0] : (dreg == 1) ? C[1] : (dreg == 2) ? C[2] : C[3];
    }
    if (gb + 4 <= GROUPS16) {
        const int lane = threadIdx.x & 63;
        const int ii   = lane & 15;
        const int src  = ((ii >> 2) << 4) + ii;
        const int jsel = lane >> 4;
        float o = 0.0f;
        #pragma unroll
        for (int j = 0; j < 4; j++) {
            const float tj = __shfl(scv[j], src, 64);
            if (jsel == j) o = tj;
        }
        __builtin_nontemporal_store(o, pout + 16 * gb + lane);
    } else {
        #pragma unroll
        for (int j = 0; j < 4; j++) {
            const int g = gb + j;
            if (is_diag && g < GROUPS16)
                __builtin_nontemporal_store(scv[j], pout + 16 * g + i);
        }
    }
}

// ================== FUSED cooperative kernel (tier a) ==================
// Phase 1 convert -> grid.sync -> Phase 2 score -> grid.sync -> Phase 3
// reduce+BCE with last-block finalize. Eliminates 2 inter-kernel gaps and
// the finalize launch (~12-15 us of the round-7 budget).
__global__ __launch_bounds__(BLOCK_THREADS, 4) void fused_all(
    const floatx4*       __restrict__ in,         // emb fp32 as float4
    const int*           __restrict__ pos_edges,
    const int*           __restrict__ neg_edges,
    unsigned char*       __restrict__ emb8,       // ws: chunk-major fp8 table
    float*               __restrict__ partial,    // ws: [8][TOTAL]
    float*               __restrict__ acc,
    unsigned int*        __restrict__ cnt,
    float*               __restrict__ out)
{
    cg::grid_group grid = cg::this_grid();
    const int tid = blockIdx.x * BLOCK_THREADS + threadIdx.x;   // < 262144

    // ---- phase 0+1: zero acc/cnt; convert (stride loop over 800000 units)
    if (tid == 0) { *acc = 0.0f; *cnt = 0u; }
    int* __restrict__ emb8i = (int*)emb8;
    for (int u = tid; u < NODE_UNITS; u += FUSED_BLOCKS * BLOCK_THREADS)
        convert_unit(in, emb8i, u);

    grid.sync();

    // ---- phase 2: score (chunk = blockIdx&7 -> XCD-local L2 slice) ----
    {
        const int chunk = blockIdx.x & 7;
        const int wid   = (blockIdx.x >> 3) * 4 + (threadIdx.x >> 6);  // [0,512)
        const int lane  = threadIdx.x & 63;
        const int i     = lane & 15;
        const int quad  = lane >> 4;
        const bool is_diag = ((i >> 2) == quad);
        const int  dreg = i & 3;
        const int  half = i & 1;
        const int  sl8  = i >> 1;
        const unsigned char* __restrict__ slice = emb8 + (size_t)chunk * SLICE_BYTES;
        float* __restrict__ pout = partial + (size_t)chunk * TOTAL;

        int sp       = (wid * NB4) >> 9;            // / FUSED_WPC (=512)
        const int se = ((wid + 1) * NB4) >> 9;
        for (; sp + 2 <= se; sp += 2)
            score8(4 * sp, i, quad, half, sl8, is_diag, dreg,
                   slice, pos_edges, neg_edges, pout);
        if (sp < se)
            score4(4 * sp, i, quad, is_diag, dreg,
                   slice, pos_edges, neg_edges, pout);
    }

    grid.sync();

    // ---- phase 3: reduce 8 partials/edge, softplus/BCE, block reduce,
    // last block (atomic counter) finalizes the mean (no 3rd grid sync).
    {
        float tsum = 0.0f;
        if (tid < TOTAL / 4) {                       // one 4-edge unit per thread
            const int e0 = 4 * tid;                  // N_EDGES%4==0: unit uniform
            float s0 = 0.f, s1 = 0.f, s2 = 0.f, s3 = 0.f;
            #pragma unroll
            for (int c = 0; c < NCHUNK; c++) {
                floatx4 v = __builtin_nontemporal_load(
                    (const floatx4*)(partial + (size_t)c * TOTAL + e0));
                s0 += v[0]; s1 += v[1]; s2 += v[2]; s3 += v[3];
            }
            const bool ip = (e0 < N_EDGES);
            const float sp0 = fmaxf(s0, 0.f) + log1pf(expf(-fabsf(s0)));
            const float sp1 = fmaxf(s1, 0.f) + log1pf(expf(-fabsf(s1)));
            const float sp2 = fmaxf(s2, 0.f) + log1pf(expf(-fabsf(s2)));
            const float sp3 = fmaxf(s3, 0.f) + log1pf(expf(-fabsf(s3)));
            tsum = (sp0 + sp1 + sp2 + sp3) - (ip ? (s0 + s1 + s2 + s3) : 0.f);
        }
        #pragma unroll
        for (int off = 32; off > 0; off >>= 1)
            tsum += __shfl_down(tsum, off, 64);
        __shared__ float ls[4];
        if ((threadIdx.x & 63) == 0) ls[threadIdx.x >> 6] = tsum;
        __syncthreads();
        if (threadIdx.x == 0) {
            atomicAdd(acc, ls[0] + ls[1] + ls[2] + ls[3]);
            __threadfence();
            const unsigned prev = atomicAdd(cnt, 1u);
            if (prev == (unsigned)(FUSED_BLOCKS - 1)) {
                __threadfence();
                const float tot = atomicAdd(acc, 0.0f);
                out[0] = tot * (1.0f / (float)TOTAL);
            }
        }
    }
}

// ============== standalone 3-kernel path (fallback if coop launch fails) =====
__global__ __launch_bounds__(BLOCK_THREADS) void convert_fp8_chunked(
    const floatx4* __restrict__ in,
    int*           __restrict__ out,
    float*         __restrict__ acc,
    unsigned int*  __restrict__ cnt)
{
    if (blockIdx.x == 0 && threadIdx.x == 0) { *acc = 0.0f; *cnt = 0u; }
    const int u = blockIdx.x * BLOCK_THREADS + threadIdx.x;  // exact fit
    convert_unit(in, out, u);
}

__global__ __launch_bounds__(BLOCK_THREADS, 4) void edge_score_chunked(
    const unsigned char* __restrict__ emb8,
    const int*           __restrict__ pos_edges,
    const int*           __restrict__ neg_edges,
    float*               __restrict__ partial)
{
    const int chunk = blockIdx.x & 7;
    const int wid   = (blockIdx.x >> 3) * 4 + (threadIdx.x >> 6);
    const int lane  = threadIdx.x & 63;
    const int i     = lane & 15;
    const int quad  = lane >> 4;
    const bool is_diag = ((i >> 2) == quad);
    const int  dreg = i & 3;
    const int  half = i & 1;
    const int  sl8  = i >> 1;
    const unsigned char* __restrict__ slice = emb8 + (size_t)chunk * SLICE_BYTES;
    float* __restrict__ pout = partial + (size_t)chunk * TOTAL;

    int sp       = (wid * NB4) >> 10;           // / WAVES_PER_CHUNK (=1024)
    const int se = ((wid + 1) * NB4) >> 10;
    for (; sp + 2 <= se; sp += 2)
        score8(4 * sp, i, quad, half, sl8, is_diag, dreg,
               slice, pos_edges, neg_edges, pout);
    if (sp < se)
        score4(4 * sp, i, quad, is_diag, dreg,
               slice, pos_edges, neg_edges, pout);
}

__global__ __launch_bounds__(BLOCK_THREADS) void reduce_bce_finalize(
    const float*  __restrict__ partial,
    float*        __restrict__ acc,
    unsigned int* __restrict__ cnt,
    float*        __restrict__ out)
{
    const int e = blockIdx.x * BLOCK_THREADS + threadIdx.x;
    float term = 0.0f;
    if (e < TOTAL) {
        float s = 0.0f;
        #pragma unroll
        for (int c = 0; c < NCHUNK; c++)
            s += partial[(size_t)c * TOTAL + e];
        const float sp = fmaxf(s, 0.0f) + log1pf(expf(-fabsf(s)));
        term = sp - (e < N_EDGES ? s : 0.0f);
    }
    #pragma unroll
    for (int off = 32; off > 0; off >>= 1)
        term += __shfl_down(term, off, 64);
    __shared__ float ls[4];
    if ((threadIdx.x & 63) == 0) ls[threadIdx.x >> 6] = term;
    __syncthreads();
    if (threadIdx.x == 0) {
        atomicAdd(acc, ls[0] + ls[1] + ls[2] + ls[3]);
        __threadfence();
        const unsigned prev = atomicAdd(cnt, 1u);
        if (prev == (unsigned)(gridDim.x - 1)) {
            __threadfence();
            const float tot = atomicAdd(acc, 0.0f);
            out[0] = tot * (1.0f / (float)TOTAL);
        }
    }
}

// ================= legacy tier b: full-table fp8 path =================
__global__ __launch_bounds__(BLOCK_THREADS) void convert_fp8(
    const float4* __restrict__ in,
    int*          __restrict__ out,
    float*        __restrict__ acc)
{
    if (blockIdx.x == 0 && threadIdx.x == 0) *acc = 0.0f;
    const int stride = gridDim.x * blockDim.x;
    for (int i = blockIdx.x * blockDim.x + threadIdx.x;
         i < TABLE_ELEMS / 4; i += stride) {
        float4 v = in[i];
        int r = 0;
        r = __builtin_amdgcn_cvt_pk_fp8_f32(v.x, v.y, r, false);
        r = __builtin_amdgcn_cvt_pk_fp8_f32(v.z, v.w, r, true);
        out[i] = r;
    }
}

#define EDGE_BLOCKS ((GROUPS16 + 3) / 4)
__global__ __launch_bounds__(BLOCK_THREADS, 4) void edge_loss_fp8(
    const unsigned char* __restrict__ emb8,
    const int*           __restrict__ pos_edges,
    const int*           __restrict__ neg_edges,
    float*               __restrict__ acc)
{
    const int wave = threadIdx.x >> 6;
    const int lane = threadIdx.x & 63;
    const int g    = blockIdx.x * 4 + wave;
    const int i    = lane & 15;
    const int quad = lane >> 4;
    const bool is_diag = ((i >> 2) == quad);
    const int  dreg    = i & 3;
    float contrib = 0.0f;
    if (g < GROUPS16) {
        const bool is_pos = (g < POS_G16);
        const int* __restrict__ edges = is_pos ? pos_edges : neg_edges;
        const int  e0 = 16 * g - (is_pos ? 0 : N_EDGES);
        const int sidx = edges[e0 + i];
        const int tidx = edges[N_EDGES + e0 + i];
        const ull2* rA = (const ull2*)(emb8 + (size_t)sidx * EMBED_DIM + quad * 16);
        const ull2* rB = (const ull2*)(emb8 + (size_t)tidx * EMBED_DIM + quad * 16);
        ull2 a[8], b[8];
        #pragma unroll
        for (int c = 0; c < 8; c++) { a[c] = rA[c * 4]; b[c] = rB[c * 4]; }
#if __has_builtin(__builtin_amdgcn_sched_barrier)
        __builtin_amdgcn_sched_barrier(0);
#endif
        floatx4 C0 = {0,0,0,0}, C1 = {0,0,0,0}, C2 = {0,0,0,0}, C3 = {0,0,0,0};
        #pragma unroll
        for (int c = 0; c < 2; c++) {
            #pragma unroll
            for (int h = 0; h < 2; h++) {
                C0 = __builtin_amdgcn_mfma_f32_16x16x32_fp8_fp8((long)a[c][h],     (long)b[c][h],     C0, 0, 0, 0);
                C1 = __builtin_amdgcn_mfma_f32_16x16x32_fp8_fp8((long)a[2 + c][h], (long)b[2 + c][h], C1, 0, 0, 0);
                C2 = __builtin_amdgcn_mfma_f32_16x16x32_fp8_fp8((long)a[4 + c][h], (long)b[4 + c][h], C2, 0, 0, 0);
                C3 = __builtin_amdgcn_mfma_f32_16x16x32_fp8_fp8((long)a[6 + c][h], (long)b[6 + c][h], C3, 0, 0, 0);
            }
        }
        floatx4 C = (C0 + C1) + (C2 + C3);
        float s = (dreg == 0) ? C[0] : (dreg == 1) ? C[1] : (dreg == 2) ? C[2] : C[3];
        float sp = fmaxf(s, 0.0f) + log1pf(expf(-fabsf(s)));
        contrib = is_diag ? (sp - (is_pos ? s : 0.0f)) : 0.0f;
    }
    #pragma unroll
    for (int off = 32; off > 0; off >>= 1)
        contrib += __shfl_down(contrib, off, 64);
    __shared__ float ls[4];
    if (lane == 0) ls[wave] = contrib;
    __syncthreads();
    if (threadIdx.x == 0)
        atomicAdd(acc, ls[0] + ls[1] + ls[2] + ls[3]);
}

// ---- tier c fallback: fp32 direct gather ----
#define N_PAIRS   (TOTAL / 2)
#define POS_PAIRS (N_EDGES / 2)
#define FB_WAVES  (CONV_BLOCKS * 4)
__global__ __launch_bounds__(BLOCK_THREADS, 8) void edge_loss_f32(
    const float* __restrict__ emb,
    const int*   __restrict__ pos_edges,
    const int*   __restrict__ neg_edges,
    float*       __restrict__ acc)
{
    const int wave  = threadIdx.x >> 6;
    const int lane  = threadIdx.x & 63;
    const int gwave = blockIdx.x * 4 + wave;
    float lsum = 0.0f;
    for (int g = gwave; g < N_PAIRS; g += FB_WAVES) {
        const bool is_pos = (g < POS_PAIRS);
        const int* __restrict__ edges = is_pos ? pos_edges : neg_edges;
        const int  e0 = 2 * g - (is_pos ? 0 : N_EDGES);
        const int s0 = edges[e0],     t0 = edges[N_EDGES + e0];
        const int s1 = edges[e0 + 1], t1 = edges[N_EDGES + e0 + 1];
        const float4* rS0 = (const float4*)(emb + (size_t)s0 * EMBED_DIM) + lane;
        const float4* rT0 = (const float4*)(emb + (size_t)t0 * EMBED_DIM) + lane;
        const float4* rS1 = (const float4*)(emb + (size_t)s1 * EMBED_DIM) + lane;
        const float4* rT1 = (const float4*)(emb + (size_t)t1 * EMBED_DIM) + lane;
        float4 a0 = rS0[0], a1 = rS0[64];
        float4 b0 = rT0[0], b1 = rT0[64];
        float4 c0 = rS1[0], c1 = rS1[64];
        float4 d0 = rT1[0], d1 = rT1[64];
        float p0 = fmaf(a0.x, b0.x, fmaf(a0.y, b0.y, fmaf(a0.z, b0.z, a0.w * b0.w)));
        float p1 = fmaf(a1.x, b1.x, fmaf(a1.y, b1.y, fmaf(a1.z, b1.z, a1.w * b1.w)));
        float q0 = fmaf(c0.x, d0.x, fmaf(c0.y, d0.y, fmaf(c0.z, d0.z, c0.w * d0.w)));
        float q1 = fmaf(c1.x, d1.x, fmaf(c1.y, d1.y, fmaf(c1.z, d1.z, c1.w * d1.w)));
        float p = p0 + p1, q = q0 + q1;
        #pragma unroll
        for (int off = 32; off > 0; off >>= 1) {
            p += __shfl_down(p, off, 64);
            q += __shfl_down(q, off, 64);
        }
        const float sp_p = fmaxf(p, 0.0f) + log1pf(expf(-fabsf(p)));
        const float sp_q = fmaxf(q, 0.0f) + log1pf(expf(-fabsf(q)));
        lsum += (lane == 0) ? (sp_p + sp_q - (is_pos ? (p + q) : 0.0f)) : 0.0f;
    }
    __shared__ float ls[4];
    if (lane == 0) ls[wave] = lsum;
    __syncthreads();
    if (threadIdx.x == 0)
        atomicAdd(acc, ls[0] + ls[1] + ls[2] + ls[3]);
}

__global__ void finalize_kernel(const float* __restrict__ acc, float* __restrict__ out)
{
    if (threadIdx.x == 0)
        out[0] = acc[0] * (1.0f / (float)TOTAL);
}

extern "C" void kernel_launch(void* const* d_in, const int* in_sizes, int n_in,
                              void* d_out, int out_size, void* d_ws, size_t ws_size,
                              hipStream_t stream) {
    const float* emb = (const float*)d_in[0];  // [50000, 512] fp32
    const int*   pos = (const int*)d_in[1];    // [2, 150000] int32
    const int*   neg = (const int*)d_in[2];    // [2, 150000] int32
    float* out = (float*)d_out;

    if (ws_size >= WS_NEEDED) {
        unsigned char* emb8    = (unsigned char*)d_ws;            // [8][N_NODES][64]
        float*         partial = (float*)((char*)d_ws + TABLE_BYTES_F8);
        float*         acc     = (float*)((char*)d_ws + WS_ACC_OFF);
        unsigned int*  cnt     = (unsigned int*)((char*)d_ws + WS_ACC_OFF + 4);

        // tier a: single cooperative kernel (convert -> score -> reduce)
        const floatx4* in4 = (const floatx4*)emb;
        void* args[] = { (void*)&in4, (void*)&pos, (void*)&neg, (void*)&emb8,
                         (void*)&partial, (void*)&acc, (void*)&cnt, (void*)&out };
        hipError_t err = hipLaunchCooperativeKernel(
            (const void*)fused_all, dim3(FUSED_BLOCKS), dim3(BLOCK_THREADS),
            args, 0, stream);
        if (err != hipSuccess) {
            // fallback: proven 3-kernel pipeline (round-7 structure)
            convert_fp8_chunked<<<CONV_BLOCKS_EXACT, BLOCK_THREADS, 0, stream>>>(
                (const floatx4*)emb, (int*)d_ws, acc, cnt);
            edge_score_chunked<<<SCORE_BLOCKS, BLOCK_THREADS, 0, stream>>>(
                emb8, pos, neg, partial);
            reduce_bce_finalize<<<RED_BLOCKS, BLOCK_THREADS, 0, stream>>>(
                partial, acc, cnt, out);
        }
    } else if (ws_size >= TABLE_BYTES_F8 + 64) {
        // tier b: full-table fp8 path
        unsigned char* emb8 = (unsigned char*)d_ws;
        float*         acc  = (float*)((char*)d_ws + TABLE_BYTES_F8);
        convert_fp8<<<CONV_BLOCKS, BLOCK_THREADS, 0, stream>>>(
            (const float4*)emb, (int*)d_ws, acc);
        edge_loss_fp8<<<EDGE_BLOCKS, BLOCK_THREADS, 0, stream>>>(emb8, pos, neg, acc);
        finalize_kernel<<<1, 64, 0, stream>>>(acc, out);
    } else {
        // tier c: fp32 direct
        float* acc = (float*)d_ws;
        (void)hipMemsetAsync(acc, 0, sizeof(float), stream);
        edge_loss_f32<<<CONV_BLOCKS, BLOCK_THREADS, 0, stream>>>(emb, pos, neg, acc);
        finalize_kernel<<<1, 64, 0, stream>>>(acc, out);
    }
}